// Round 1
// 234.002 us; speedup vs baseline: 1.1913x; 1.1913x over previous
//
#include <hip/hip_runtime.h>

#define BATCH 8
#define CH    64
#define HH    112
#define WW    112
#define HW    (HH * WW)          // 12544
#define NP    (BATCH * HW)       // 100352 pixels
#define TAPS  25
#define MIDC  256
#define PIX   64                 // pixels per block (= 1 wave-width group)
#define CPW   16                 // channels per wave (4 waves * 16 = 64)
#define NBLK  (NP / PIX)         // 1568 blocks
#define NXCD  8
#define CPX   (NBLK / NXCD)      // 196 blocks per XCD == blocks per image

// ---------------------------------------------------------------------------
// Kernel A: fold conv2 (1x1, 256->25) into conv1 weights.
//   weff[c][tap][o] = sum_mid w2[o][mid] * w1[mid][c][tap]
//   beff[o]         = b2[o] + sum_mid w2[o][mid] * b1[mid]
// One output element per thread; 157 blocks so the launch fills the chip.
// Lanes within a 25-lane group share (c,o): w1 reads are contiguous 25-float
// runs, w2 reads broadcast. Two accumulators break the serial FMA chain.
// ---------------------------------------------------------------------------
#define WEFF_N (CH * TAPS * TAPS)   // 40000
__global__ __launch_bounds__(256) void weff_kernel(
    const float* __restrict__ w1, const float* __restrict__ b1,
    const float* __restrict__ w2, const float* __restrict__ b2,
    float* __restrict__ weff, float* __restrict__ beff) {
  const int id = blockIdx.x * 256 + threadIdx.x;
  if (id < WEFF_N) {
    const int tap = id % TAPS;
    const int t2  = id / TAPS;
    const int o   = t2 % TAPS;
    const int c   = t2 / TAPS;
    const float* w2o = w2 + o * MIDC;
    float a0 = 0.f, a1 = 0.f;
    #pragma unroll 4
    for (int mid = 0; mid < MIDC; mid += 2) {
      a0 = fmaf(w1[(mid * CH + c) * TAPS + tap],       w2o[mid],     a0);
      a1 = fmaf(w1[((mid + 1) * CH + c) * TAPS + tap], w2o[mid + 1], a1);
    }
    weff[(c * TAPS + tap) * TAPS + o] = a0 + a1;
  } else if (id < WEFF_N + TAPS) {
    const int o = id - WEFF_N;
    const float* w2o = w2 + o * MIDC;
    float b = b2[o];
    for (int mid = 0; mid < MIDC; ++mid) b = fmaf(w2o[mid], b1[mid], b);
    beff[o] = b;
  }
}

// ---------------------------------------------------------------------------
// Kernel B: fused logits -> cross-wave reduce -> softmax -> weighted gather.
// Block = 256 threads = 4 waves; 64 pixels/block (lane = pixel); wave w owns
// channels [16w, 16w+16).
//
// XCD swizzle: blockIdx n -> XCD n%8 (empirical round-robin). Remap so XCD k
// gets logical blocks [k*196, (k+1)*196) == exactly image k (3.2 MB < 4 MB
// per-XCD L2). All tap-halo reuse and the phase-2 re-read become L2 hits:
// FETCH_SIZE should collapse from ~310 MB to ~compulsory traffic.
// ---------------------------------------------------------------------------
__global__ __launch_bounds__(256, 6) void picanet_main(
    const float* __restrict__ x, const float* __restrict__ weff,
    const float* __restrict__ beff, float* __restrict__ out) {
  __shared__ float red[4 * PIX * TAPS];       // 25.6 KB -> 6 blocks/CU by LDS

  const int lane = threadIdx.x & 63;
  const int wave = threadIdx.x >> 6;
  // Force wave-uniformity so weight addresses stay scalar (s_load path).
  const int c0 = __builtin_amdgcn_readfirstlane(wave * CPW);

  // XCD-aware bijective remap (NBLK % 8 == 0).
  const int lb = (blockIdx.x & (NXCD - 1)) * CPX + (blockIdx.x >> 3);
  const int p  = lb * PIX + lane;             // NP % 64 == 0, no tail
  const int b  = p / HW;                      // == lb / CPX (one image per XCD)
  const int hw = p % HW;
  const int h  = hw / WW;
  const int w  = hw % WW;

  const float* xb = x + (size_t)b * CH * HW + (size_t)c0 * HW;
  const float* wc = weff + (size_t)c0 * TAPS * TAPS;

  // ---- Phase 1: partial logits over this wave's 16 channels ----
  float s[TAPS];
  #pragma unroll
  for (int o = 0; o < TAPS; ++o) s[o] = 0.f;

  #pragma unroll 1
  for (int tap = 0; tap < TAPS; ++tap) {
    int i = tap / 5, j = tap % 5;
    int yy = h + 2 * i - 4;
    int xx = w + 2 * j - 4;
    // Exec-mask skip instead of xv*mask: invalid lanes contribute exactly 0,
    // interior lanes drop the per-load v_mul.
    if (yy >= 0 && yy < HH && xx >= 0 && xx < WW) {
      int offt = yy * WW + xx;
      const float* wt = wc + tap * TAPS;
      #pragma unroll
      for (int c = 0; c < CPW; ++c) {
        float xv = xb[(size_t)c * HW + offt];
        const float* wp = wt + c * (TAPS * TAPS);   // uniform -> scalar loads
        #pragma unroll
        for (int o = 0; o < TAPS; ++o) s[o] = fmaf(xv, wp[o], s[o]);
      }
    }
  }

  #pragma unroll
  for (int o = 0; o < TAPS; ++o) red[(wave * PIX + lane) * TAPS + o] = s[o];
  __syncthreads();

  // ---- Softmax: all 4 waves participate, 16 pixels each (4x shorter
  // serial section than wave0-only). Thread for pixel px reads its 4
  // partials and overwrites only red[px*TAPS+o] (own slot) -> race-free.
  // No validity masking needed here: phase 2 skips invalid taps.
  if (lane < CPW) {
    const int px = (wave << 4) + lane;
    float t[TAPS];
    #pragma unroll
    for (int o = 0; o < TAPS; ++o)
      t[o] = red[px * TAPS + o] + red[(PIX + px) * TAPS + o] +
             red[(2 * PIX + px) * TAPS + o] + red[(3 * PIX + px) * TAPS + o] +
             beff[o];
    float m = t[0];
    #pragma unroll
    for (int o = 1; o < TAPS; ++o) m = fmaxf(m, t[o]);
    float sum = 0.f;
    #pragma unroll
    for (int o = 0; o < TAPS; ++o) { t[o] = __expf(t[o] - m); sum += t[o]; }
    float inv = 1.f / sum;
    #pragma unroll
    for (int o = 0; o < TAPS; ++o) red[px * TAPS + o] = t[o] * inv;
  }
  __syncthreads();

  // ---- Phase 2: out[b,c,h,w] = sum_tap sfin[tap] * x[b,c,tap(h,w)] ----
  float acc[CPW];
  #pragma unroll
  for (int c = 0; c < CPW; ++c) acc[c] = 0.f;

  #pragma unroll 1
  for (int tap = 0; tap < TAPS; ++tap) {
    int i = tap / 5, j = tap % 5;
    int yy = h + 2 * i - 4;
    int xx = w + 2 * j - 4;
    float sv = red[lane * TAPS + tap];     // dynamic index stays in LDS
    if (yy >= 0 && yy < HH && xx >= 0 && xx < WW) {
      int offt = yy * WW + xx;
      #pragma unroll
      for (int c = 0; c < CPW; ++c)
        acc[c] = fmaf(sv, xb[(size_t)c * HW + offt], acc[c]);
    }
  }

  float* ob = out + (size_t)b * CH * HW + (size_t)c0 * HW + hw;
  #pragma unroll
  for (int c = 0; c < CPW; ++c) ob[c * HW] = acc[c];
}

extern "C" void kernel_launch(void* const* d_in, const int* in_sizes, int n_in,
                              void* d_out, int out_size, void* d_ws, size_t ws_size,
                              hipStream_t stream) {
  const float* x  = (const float*)d_in[0];
  const float* w1 = (const float*)d_in[1];
  const float* b1 = (const float*)d_in[2];
  const float* w2 = (const float*)d_in[3];
  const float* b2 = (const float*)d_in[4];
  float* out  = (float*)d_out;
  float* weff = (float*)d_ws;                       // 40000 floats
  float* beff = weff + CH * TAPS * TAPS;            // 25 floats

  weff_kernel<<<(WEFF_N + TAPS + 255) / 256, 256, 0, stream>>>(w1, b1, w2, b2, weff, beff);
  picanet_main<<<NBLK, 256, 0, stream>>>(x, weff, beff, out);
}

// Round 2
// 221.683 us; speedup vs baseline: 1.2575x; 1.0556x over previous
//
#include <hip/hip_runtime.h>

#define BATCH 8
#define CH    64
#define HH    112
#define WW    112
#define HW    (HH * WW)          // 12544
#define NP    (BATCH * HW)       // 100352 pixels
#define TAPS  25
#define MIDC  256
#define PIX   64                 // pixels per block (= 1 wave-width group)
#define CPW   16                 // channels per wave (4 waves * 16 = 64)
#define NBLK  (NP / PIX)         // 1568 blocks
#define NXCD  8
#define CPX   (NBLK / NXCD)      // 196 blocks per XCD == blocks per image

// ---------------------------------------------------------------------------
// Kernel A: fold conv2 (1x1, 256->25) into conv1 weights.
//   weff[c][tap][o] = sum_mid w2[o][mid] * w1[mid][c][tap]
//   beff[o]         = b2[o] + sum_mid w2[o][mid] * b1[mid]
// One output element per thread; 157 blocks fill the chip.
// ---------------------------------------------------------------------------
#define WEFF_N (CH * TAPS * TAPS)   // 40000
__global__ __launch_bounds__(256) void weff_kernel(
    const float* __restrict__ w1, const float* __restrict__ b1,
    const float* __restrict__ w2, const float* __restrict__ b2,
    float* __restrict__ weff, float* __restrict__ beff) {
  const int id = blockIdx.x * 256 + threadIdx.x;
  if (id < WEFF_N) {
    const int tap = id % TAPS;
    const int t2  = id / TAPS;
    const int o   = t2 % TAPS;
    const int c   = t2 / TAPS;
    const float* w2o = w2 + o * MIDC;
    float a0 = 0.f, a1 = 0.f;
    #pragma unroll 4
    for (int mid = 0; mid < MIDC; mid += 2) {
      a0 = fmaf(w1[(mid * CH + c) * TAPS + tap],       w2o[mid],     a0);
      a1 = fmaf(w1[((mid + 1) * CH + c) * TAPS + tap], w2o[mid + 1], a1);
    }
    weff[(c * TAPS + tap) * TAPS + o] = a0 + a1;
  } else if (id < WEFF_N + TAPS) {
    const int o = id - WEFF_N;
    const float* w2o = w2 + o * MIDC;
    float b = b2[o];
    for (int mid = 0; mid < MIDC; ++mid) b = fmaf(w2o[mid], b1[mid], b);
    beff[o] = b;
  }
}

// ---------------------------------------------------------------------------
// Kernel B: fused logits -> tree reduce -> softmax -> weighted gather.
// Block = 256 threads = 4 waves; 64 pixels/block (lane = pixel); wave w owns
// channels [16w, 16w+16).
//
// R2 changes vs R1:
//  - LDS 25.6 KB -> 12.8 KB tree reduce: waves 2,3 store partials; waves 0,1
//    add them to their own; wave 1 stores its sum; wave 0 adds it, then does
//    the softmax with a FULL 64-lane wave (one pixel per lane).
//    LDS <= 20 KB + VGPR <= 64 + __launch_bounds__(256,8) -> 8 blocks/CU
//    (32 waves/CU, hardware cap). All 1568 blocks co-resident: no tail, and
//    2048-resident-wave latency hiding for the ~200-cycle L2-hit x loads.
//  - XCD swizzle retained: image b pinned to XCD b (3.2 MB < 4 MB L2).
// ---------------------------------------------------------------------------
__global__ __launch_bounds__(256, 8) void picanet_main(
    const float* __restrict__ x, const float* __restrict__ weff,
    const float* __restrict__ beff, float* __restrict__ out) {
  __shared__ float red[2 * PIX * TAPS];       // 12.8 KB

  const int lane = threadIdx.x & 63;
  const int wave = threadIdx.x >> 6;
  // Force wave-uniformity so weight addresses stay scalar (s_load path).
  const int c0 = __builtin_amdgcn_readfirstlane(wave * CPW);

  // XCD-aware bijective remap (NBLK % 8 == 0).
  const int lb = (blockIdx.x & (NXCD - 1)) * CPX + (blockIdx.x >> 3);
  const int p  = lb * PIX + lane;             // NP % 64 == 0, no tail
  const int b  = p / HW;                      // == lb / CPX (one image per XCD)
  const int hw = p % HW;
  const int h  = hw / WW;
  const int w  = hw % WW;

  const float* xb = x + (size_t)b * CH * HW + (size_t)c0 * HW;
  const float* wc = weff + (size_t)c0 * TAPS * TAPS;

  // ---- Phase 1: partial logits over this wave's 16 channels ----
  float s[TAPS];
  #pragma unroll
  for (int o = 0; o < TAPS; ++o) s[o] = 0.f;

  #pragma unroll 1
  for (int tap = 0; tap < TAPS; ++tap) {
    int i = tap / 5, j = tap % 5;
    int yy = h + 2 * i - 4;
    int xx = w + 2 * j - 4;
    // Exec-mask skip: invalid lanes contribute exactly 0 (matches zero-pad).
    if (yy >= 0 && yy < HH && xx >= 0 && xx < WW) {
      int offt = yy * WW + xx;
      const float* wt = wc + tap * TAPS;
      #pragma unroll
      for (int c = 0; c < CPW; ++c) {
        float xv = xb[(size_t)c * HW + offt];
        const float* wp = wt + c * (TAPS * TAPS);   // uniform -> scalar loads
        #pragma unroll
        for (int o = 0; o < TAPS; ++o) s[o] = fmaf(xv, wp[o], s[o]);
      }
    }
  }

  // ---- Tree reduce across waves (12.8 KB instead of 25.6 KB) ----
  if (wave >= 2) {
    float* dst = red + (wave - 2) * (PIX * TAPS);   // wave2->buf0, wave3->buf1
    #pragma unroll
    for (int o = 0; o < TAPS; ++o) dst[lane * TAPS + o] = s[o];
  }
  __syncthreads();
  if (wave < 2) {
    const float* srcp = red + wave * (PIX * TAPS);  // wave0+=buf0, wave1+=buf1
    #pragma unroll
    for (int o = 0; o < TAPS; ++o) s[o] += srcp[lane * TAPS + o];
  }
  if (wave == 1) {                                  // wave1 sum -> buf1
    float* dst = red + (PIX * TAPS);
    #pragma unroll
    for (int o = 0; o < TAPS; ++o) dst[lane * TAPS + o] = s[o];
  }
  __syncthreads();

  // ---- Softmax: full 64-lane wave 0, one pixel per lane ----
  if (wave == 0) {
    const float* srcp = red + (PIX * TAPS);
    float t[TAPS];
    #pragma unroll
    for (int o = 0; o < TAPS; ++o)
      t[o] = s[o] + srcp[lane * TAPS + o] + beff[o];
    float m = t[0];
    #pragma unroll
    for (int o = 1; o < TAPS; ++o) m = fmaxf(m, t[o]);
    float sum = 0.f;
    #pragma unroll
    for (int o = 0; o < TAPS; ++o) { t[o] = __expf(t[o] - m); sum += t[o]; }
    float inv = 1.f / sum;
    #pragma unroll
    for (int o = 0; o < TAPS; ++o) red[lane * TAPS + o] = t[o] * inv;
  }
  __syncthreads();

  // ---- Phase 2: out[b,c,h,w] = sum_tap sfin[tap] * x[b,c,tap(h,w)] ----
  float acc[CPW];
  #pragma unroll
  for (int c = 0; c < CPW; ++c) acc[c] = 0.f;

  #pragma unroll 1
  for (int tap = 0; tap < TAPS; ++tap) {
    int i = tap / 5, j = tap % 5;
    int yy = h + 2 * i - 4;
    int xx = w + 2 * j - 4;
    float sv = red[lane * TAPS + tap];     // dynamic index stays in LDS
    if (yy >= 0 && yy < HH && xx >= 0 && xx < WW) {
      int offt = yy * WW + xx;
      #pragma unroll
      for (int c = 0; c < CPW; ++c)
        acc[c] = fmaf(sv, xb[(size_t)c * HW + offt], acc[c]);
    }
  }

  float* ob = out + (size_t)b * CH * HW + (size_t)c0 * HW + hw;
  #pragma unroll
  for (int c = 0; c < CPW; ++c) ob[c * HW] = acc[c];
}

extern "C" void kernel_launch(void* const* d_in, const int* in_sizes, int n_in,
                              void* d_out, int out_size, void* d_ws, size_t ws_size,
                              hipStream_t stream) {
  const float* x  = (const float*)d_in[0];
  const float* w1 = (const float*)d_in[1];
  const float* b1 = (const float*)d_in[2];
  const float* w2 = (const float*)d_in[3];
  const float* b2 = (const float*)d_in[4];
  float* out  = (float*)d_out;
  float* weff = (float*)d_ws;                       // 40000 floats
  float* beff = weff + CH * TAPS * TAPS;            // 25 floats

  weff_kernel<<<(WEFF_N + TAPS + 255) / 256, 256, 0, stream>>>(w1, b1, w2, b2, weff, beff);
  picanet_main<<<NBLK, 256, 0, stream>>>(x, weff, beff, out);
}

// Round 3
// 220.243 us; speedup vs baseline: 1.2657x; 1.0065x over previous
//
#include <hip/hip_runtime.h>

#define BATCH 8
#define CH    64
#define HH    112
#define WW    112
#define HW    (HH * WW)          // 12544
#define NP    (BATCH * HW)       // 100352 pixels
#define TAPS  25
#define MIDC  256
#define PIX   64                 // pixels per block (= 1 wave-width group)
#define CPW   16                 // channels per wave (4 waves * 16 = 64)
#define NBLK  (NP / PIX)         // 1568 blocks
#define NXCD  8
#define CPX   (NBLK / NXCD)      // 196 blocks per XCD == blocks per image

// ---------------------------------------------------------------------------
// Kernel A: fold conv2 (1x1, 256->25) into conv1 weights.
//   weff[c][tap][o] = sum_mid w2[o][mid] * w1[mid][c][tap]
//   beff[o]         = b2[o] + sum_mid w2[o][mid] * b1[mid]
// One output element per thread; 157 blocks fill the chip.
// ---------------------------------------------------------------------------
#define WEFF_N (CH * TAPS * TAPS)   // 40000
__global__ __launch_bounds__(256) void weff_kernel(
    const float* __restrict__ w1, const float* __restrict__ b1,
    const float* __restrict__ w2, const float* __restrict__ b2,
    float* __restrict__ weff, float* __restrict__ beff) {
  const int id = blockIdx.x * 256 + threadIdx.x;
  if (id < WEFF_N) {
    const int tap = id % TAPS;
    const int t2  = id / TAPS;
    const int o   = t2 % TAPS;
    const int c   = t2 / TAPS;
    const float* w2o = w2 + o * MIDC;
    float a0 = 0.f, a1 = 0.f;
    #pragma unroll 4
    for (int mid = 0; mid < MIDC; mid += 2) {
      a0 = fmaf(w1[(mid * CH + c) * TAPS + tap],       w2o[mid],     a0);
      a1 = fmaf(w1[((mid + 1) * CH + c) * TAPS + tap], w2o[mid + 1], a1);
    }
    weff[(c * TAPS + tap) * TAPS + o] = a0 + a1;
  } else if (id < WEFF_N + TAPS) {
    const int o = id - WEFF_N;
    const float* w2o = w2 + o * MIDC;
    float b = b2[o];
    for (int mid = 0; mid < MIDC; ++mid) b = fmaf(w2o[mid], b1[mid], b);
    beff[o] = b;
  }
}

// ---------------------------------------------------------------------------
// Kernel B: fused logits -> tree reduce -> softmax -> weighted gather.
// Block = 256 threads = 4 waves; 64 pixels/block (lane = pixel); wave w owns
// channels [16w, 16w+16).
//
// R3 changes vs R2:
//  - __launch_bounds__(256, 6) not (256,8): grid supplies only 6.125
//    blocks/CU, so 8-block residency was unattainable; the 8-wave bound
//    squeezed VGPR to 32 (< 25 accumulators + load pipeline), forcing the
//    compiler to trickle the 16 per-tap loads 2-3 at a time with exposed
//    ~200cy vmcnt stalls. Cap 6 waves/SIMD -> ~84 VGPR budget.
//  - Phase 1 loads all 16 channel values into xv[16] BEFORE the 400-FMA
//    block: 16 loads in flight, one latency exposure per ~1600 busy cycles.
//  - XCD swizzle + 12.8 KB tree reduce retained.
// ---------------------------------------------------------------------------
__global__ __launch_bounds__(256, 6) void picanet_main(
    const float* __restrict__ x, const float* __restrict__ weff,
    const float* __restrict__ beff, float* __restrict__ out) {
  __shared__ float red[2 * PIX * TAPS];       // 12.8 KB

  const int lane = threadIdx.x & 63;
  const int wave = threadIdx.x >> 6;
  // Force wave-uniformity so weight addresses stay scalar (s_load path).
  const int c0 = __builtin_amdgcn_readfirstlane(wave * CPW);

  // XCD-aware bijective remap (NBLK % 8 == 0): image b pinned to XCD b,
  // 3.2 MB image < 4 MB per-XCD L2 -> all x reuse is L2-hit.
  const int lb = (blockIdx.x & (NXCD - 1)) * CPX + (blockIdx.x >> 3);
  const int p  = lb * PIX + lane;             // NP % 64 == 0, no tail
  const int b  = p / HW;                      // == lb / CPX (one image per XCD)
  const int hw = p % HW;
  const int h  = hw / WW;
  const int w  = hw % WW;

  const float* xb = x + (size_t)b * CH * HW + (size_t)c0 * HW;
  const float* wc = weff + (size_t)c0 * TAPS * TAPS;

  // ---- Phase 1: partial logits over this wave's 16 channels ----
  float s[TAPS];
  #pragma unroll
  for (int o = 0; o < TAPS; ++o) s[o] = 0.f;

  #pragma unroll 1
  for (int tap = 0; tap < TAPS; ++tap) {
    int i = tap / 5, j = tap % 5;
    int yy = h + 2 * i - 4;
    int xx = w + 2 * j - 4;
    // Exec-mask skip: invalid lanes contribute exactly 0 (matches zero-pad).
    if (yy >= 0 && yy < HH && xx >= 0 && xx < WW) {
      const float* xp = xb + yy * WW + xx;
      // Batch all 16 channel loads first: with the VGPR headroom from
      // launch_bounds(256,6) these stay in flight simultaneously.
      float xv[CPW];
      #pragma unroll
      for (int c = 0; c < CPW; ++c) xv[c] = xp[(size_t)c * HW];
      const float* wt = wc + tap * TAPS;
      #pragma unroll
      for (int c = 0; c < CPW; ++c) {
        const float* wp = wt + c * (TAPS * TAPS);   // uniform -> scalar loads
        #pragma unroll
        for (int o = 0; o < TAPS; ++o) s[o] = fmaf(xv[c], wp[o], s[o]);
      }
    }
  }

  // ---- Tree reduce across waves (12.8 KB) ----
  if (wave >= 2) {
    float* dst = red + (wave - 2) * (PIX * TAPS);   // wave2->buf0, wave3->buf1
    #pragma unroll
    for (int o = 0; o < TAPS; ++o) dst[lane * TAPS + o] = s[o];
  }
  __syncthreads();
  if (wave < 2) {
    const float* srcp = red + wave * (PIX * TAPS);  // wave0+=buf0, wave1+=buf1
    #pragma unroll
    for (int o = 0; o < TAPS; ++o) s[o] += srcp[lane * TAPS + o];
  }
  if (wave == 1) {                                  // wave1 sum -> buf1
    float* dst = red + (PIX * TAPS);
    #pragma unroll
    for (int o = 0; o < TAPS; ++o) dst[lane * TAPS + o] = s[o];
  }
  __syncthreads();

  // ---- Softmax: full 64-lane wave 0, one pixel per lane ----
  if (wave == 0) {
    const float* srcp = red + (PIX * TAPS);
    float t[TAPS];
    #pragma unroll
    for (int o = 0; o < TAPS; ++o)
      t[o] = s[o] + srcp[lane * TAPS + o] + beff[o];
    float m = t[0];
    #pragma unroll
    for (int o = 1; o < TAPS; ++o) m = fmaxf(m, t[o]);
    float sum = 0.f;
    #pragma unroll
    for (int o = 0; o < TAPS; ++o) { t[o] = __expf(t[o] - m); sum += t[o]; }
    float inv = 1.f / sum;
    #pragma unroll
    for (int o = 0; o < TAPS; ++o) red[lane * TAPS + o] = t[o] * inv;
  }
  __syncthreads();

  // ---- Phase 2: out[b,c,h,w] = sum_tap sfin[tap] * x[b,c,tap(h,w)] ----
  float acc[CPW];
  #pragma unroll
  for (int c = 0; c < CPW; ++c) acc[c] = 0.f;

  #pragma unroll 1
  for (int tap = 0; tap < TAPS; ++tap) {
    int i = tap / 5, j = tap % 5;
    int yy = h + 2 * i - 4;
    int xx = w + 2 * j - 4;
    float sv = red[lane * TAPS + tap];     // dynamic index stays in LDS
    if (yy >= 0 && yy < HH && xx >= 0 && xx < WW) {
      const float* xp = xb + yy * WW + xx;
      #pragma unroll
      for (int c = 0; c < CPW; ++c)
        acc[c] = fmaf(sv, xp[(size_t)c * HW], acc[c]);
    }
  }

  float* ob = out + (size_t)b * CH * HW + (size_t)c0 * HW + hw;
  #pragma unroll
  for (int c = 0; c < CPW; ++c) ob[c * HW] = acc[c];
}

extern "C" void kernel_launch(void* const* d_in, const int* in_sizes, int n_in,
                              void* d_out, int out_size, void* d_ws, size_t ws_size,
                              hipStream_t stream) {
  const float* x  = (const float*)d_in[0];
  const float* w1 = (const float*)d_in[1];
  const float* b1 = (const float*)d_in[2];
  const float* w2 = (const float*)d_in[3];
  const float* b2 = (const float*)d_in[4];
  float* out  = (float*)d_out;
  float* weff = (float*)d_ws;                       // 40000 floats
  float* beff = weff + CH * TAPS * TAPS;            // 25 floats

  weff_kernel<<<(WEFF_N + TAPS + 255) / 256, 256, 0, stream>>>(w1, b1, w2, b2, weff, beff);
  picanet_main<<<NBLK, 256, 0, stream>>>(x, weff, beff, out);
}